// Round 6
// baseline (440.884 us; speedup 1.0000x reference)
//
#include <hip/hip_runtime.h>
#include <math.h>

#define Bn 32
#define Cn 256
#define Hn 64
#define Wn 64
#define MIP 8
#define OUP 256
#define BN_EPS 1e-5f

typedef float vfloat4 __attribute__((ext_vector_type(4)));  // native vec for NT ld/st

// ---------------------------------------------------------------------------
// R6 DIAGNOSTIC ROUND (= R4 probe, resubmitted after two infra failures;
// structure identical to R3 except apply is launched 5x). apply_kernel is
// pure/idempotent, so duplicates are bit-identical. dur_us delta vs R3
// (268.4 us) = 4 x (apply + boundary). If apply >= 77 us it enters the
// rocprof top-5 WITH its FETCH/WRITE counters, directly showing whether its
// NT x-reads come from HBM (FETCH ~134 MB => NT bypasses L3, drop NT loads)
// or from L3 (FETCH small => slack lives elsewhere).
// ---------------------------------------------------------------------------

// ---------------------------------------------------------------------------
// Kernel 1: per-(b,c) stats -> A[b][c][s], s in [0,128)
//   s<64:  a_h[h] = (rowsum[h] + softmax_h(rowmax)[h]) / 64
//   s>=64: a_w[w] = (colsum[w] + softmax_w(colmax)[w]) / 64
// (uses: mean_W(bias_h*bias_w) = bias_h/64 since softmax_w sums to 1)
// R2 LESSON: do NOT fuse stages via __threadfence()+atomic last-block pattern
// -- device-scope fences are chip-wide L2 writeback events on MI355X; 8192 of
// them serialized the machine (1161 us at 0.84% HBM).
// ---------------------------------------------------------------------------
__global__ __launch_bounds__(256) void stats_kernel(const float* __restrict__ x,
                                                    float* __restrict__ A) {
    const int bc = blockIdx.x;                       // b*Cn + c
    const float* xp = x + (size_t)bc * (Hn * Wn);
    __shared__ float tile[Hn * 65];                  // pitch 65: row & col conflict-free
    __shared__ float pmax[256], psum[256];
    const int t = threadIdx.x;

    // load 64x64 tile, float4-vectorized, coalesced (normal loads: WANT x in
    // L2/L3 for apply_kernel's re-read)
#pragma unroll
    for (int k = 0; k < 4; ++k) {
        int i4  = t + 256 * k;                       // float4 index 0..1023
        int idx = i4 * 4;
        int h = idx >> 6;
        int w = idx & 63;
        float4 v = ((const float4*)xp)[i4];
        float* dst = &tile[h * 65 + w];
        dst[0] = v.x; dst[1] = v.y; dst[2] = v.z; dst[3] = v.w;
    }
    __syncthreads();

    // half-range partial reductions (32 serial LDS reads each)
    {
        const int wv   = t >> 6;                     // wave id 0..3
        const int lane = t & 63;
        float m = -INFINITY, sm = 0.f;
        if ((wv & 1) == 0) {                         // waves 0,2: row lane, half (wv>>1)
            const int h = lane, w0 = (wv >> 1) * 32;
#pragma unroll 8
            for (int w = w0; w < w0 + 32; ++w) {
                float v = tile[h * 65 + w];
                m = fmaxf(m, v); sm += v;
            }
        } else {                                     // waves 1,3: col lane, half (wv>>1)
            const int w = lane, h0 = (wv >> 1) * 32;
#pragma unroll 8
            for (int h = h0; h < h0 + 32; ++h) {
                float v = tile[h * 65 + w];
                m = fmaxf(m, v); sm += v;
            }
        }
        pmax[t] = m; psum[t] = sm;
    }
    __syncthreads();

    if (t < 128) {
        float red_max = fmaxf(pmax[t], pmax[t + 128]);
        float red_sum = psum[t] + psum[t + 128];
        // softmax across the 64 lanes of this wave (wave0 = rows, wave1 = cols)
        float m = red_max;
#pragma unroll
        for (int off = 32; off > 0; off >>= 1) m = fmaxf(m, __shfl_xor(m, off));
        float e = __expf(red_max - m);
        float se = e;
#pragma unroll
        for (int off = 32; off > 0; off >>= 1) se += __shfl_xor(se, off);
        float a = (red_sum + e / se) * (1.0f / 64.0f);
        A[(size_t)bc * 128 + t] = a;
    }
}

// ---------------------------------------------------------------------------
// Kernel 2 (tiny): yact[b][m][s] = hswish(BN(sum_c w1[m][c] * A[b][c][s]))
//   1024 threads: s = t&127, K=256 split 8-way (32 c per thread), LDS combine.
// ---------------------------------------------------------------------------
__global__ __launch_bounds__(1024) void ymix_kernel(const float* __restrict__ A,
                                                    const float* __restrict__ w1,
                                                    const float* __restrict__ bn_gamma,
                                                    const float* __restrict__ bn_beta,
                                                    const float* __restrict__ bn_mean,
                                                    const float* __restrict__ bn_var,
                                                    float* __restrict__ yact) {
    const int b = blockIdx.x;
    const int t = threadIdx.x;
    const int s     = t & 127;
    const int chunk = t >> 7;                        // 0..7

    const float* Ab = A + (size_t)b * Cn * 128;

    float acc[MIP];
#pragma unroll
    for (int m = 0; m < MIP; ++m) acc[m] = 0.f;

    const int c0 = chunk * 32;
    for (int c = c0; c < c0 + 32; ++c) {
        float a = Ab[(size_t)c * 128 + s];           // coalesced over s
#pragma unroll
        for (int m = 0; m < MIP; ++m)
            acc[m] += w1[m * Cn + c] * a;            // wave-uniform scalar load
    }

    __shared__ float red[7][MIP][128];               // chunks 1..7
    if (chunk > 0) {
#pragma unroll
        for (int m = 0; m < MIP; ++m) red[chunk - 1][m][s] = acc[m];
    }
    __syncthreads();
    if (chunk == 0) {
#pragma unroll
        for (int m = 0; m < MIP; ++m) {
            float v = acc[m];
#pragma unroll
            for (int k = 0; k < 7; ++k) v += red[k][m][s];
            float sc = bn_gamma[m] * rsqrtf(bn_var[m] + BN_EPS);
            float sh = bn_beta[m] - bn_mean[m] * sc;
            v = v * sc + sh;
            v = v * fminf(fmaxf(v + 3.0f, 0.0f), 6.0f) * (1.0f / 6.0f); // hswish
            yact[(size_t)b * (MIP * 128) + m * 128 + s] = v;
        }
    }
}

// ---------------------------------------------------------------------------
// Kernel 3: per-(b,c) gate-compute + apply.
//   gs[s] = sigmoid(sum_m W2[c][m] * yact[b][m][s])  (W2 = wh for s<64, ww else)
//   out[b,c,h,w] = x[b,c,h,w] * gs[h] * gs[64+w]
//   NT loads for x (last use) + NT stores for out (never re-read).
// ---------------------------------------------------------------------------
__global__ __launch_bounds__(256) void apply_kernel(const float* __restrict__ x,
                                                    const float* __restrict__ yact,
                                                    const float* __restrict__ wh,
                                                    const float* __restrict__ ww,
                                                    float* __restrict__ out) {
    const int bc = blockIdx.x;
    const int b  = bc >> 8;
    const int c  = bc & 255;
    const float* xp = x + (size_t)bc * (Hn * Wn);
    float* op = out + (size_t)bc * (Hn * Wn);

    __shared__ float gs[128];                        // [0,64): g_h, [64,128): g_w
    const int t = threadIdx.x;
    if (t < 128) {
        const float* w2row = (t < 64) ? (wh + c * MIP) : (ww + c * MIP); // wave-uniform
        const float* yb = yact + (size_t)b * (MIP * 128);
        float g = 0.f;
#pragma unroll
        for (int m = 0; m < MIP; ++m)
            g += w2row[m] * yb[m * 128 + t];         // coalesced over t
        gs[t] = 1.0f / (1.0f + __expf(-g));
    }
    __syncthreads();

#pragma unroll
    for (int k = 0; k < 4; ++k) {
        int i4  = t + 256 * k;
        int idx = i4 * 4;
        int h = idx >> 6;
        int w = idx & 63;                            // w % 4 == 0 -> aligned b128
        vfloat4 v = __builtin_nontemporal_load(&((const vfloat4*)xp)[i4]);
        float gh = gs[h];
        float4 gw = *(const float4*)&gs[64 + w];     // one ds_read_b128
        vfloat4 r;
        r.x = v.x * gh * gw.x;
        r.y = v.y * gh * gw.y;
        r.z = v.z * gh * gw.z;
        r.w = v.w * gh * gw.w;
        __builtin_nontemporal_store(r, &((vfloat4*)op)[i4]);
    }
}

extern "C" void kernel_launch(void* const* d_in, const int* in_sizes, int n_in,
                              void* d_out, int out_size, void* d_ws, size_t ws_size,
                              hipStream_t stream) {
    const float* x        = (const float*)d_in[0];
    const float* w1       = (const float*)d_in[1];
    const float* bn_gamma = (const float*)d_in[2];
    const float* bn_beta  = (const float*)d_in[3];
    const float* bn_mean  = (const float*)d_in[4];
    const float* bn_var   = (const float*)d_in[5];
    const float* wh       = (const float*)d_in[6];
    const float* ww       = (const float*)d_in[7];
    float* out = (float*)d_out;

    float* A    = (float*)d_ws;                            // Bn*Cn*128 floats = 4 MiB
    float* yact = A + (size_t)Bn * Cn * 128;               // Bn*MIP*128 floats = 128 KiB

    stats_kernel<<<Bn * Cn, 256, 0, stream>>>(x, A);
    ymix_kernel<<<Bn, 1024, 0, stream>>>(A, w1, bn_gamma, bn_beta, bn_mean,
                                         bn_var, yact);
    // apply x5: idempotent duplicates for the duration probe (see header note)
    apply_kernel<<<Bn * Cn, 256, 0, stream>>>(x, yact, wh, ww, out);
    apply_kernel<<<Bn * Cn, 256, 0, stream>>>(x, yact, wh, ww, out);
    apply_kernel<<<Bn * Cn, 256, 0, stream>>>(x, yact, wh, ww, out);
    apply_kernel<<<Bn * Cn, 256, 0, stream>>>(x, yact, wh, ww, out);
    apply_kernel<<<Bn * Cn, 256, 0, stream>>>(x, yact, wh, ww, out);
}

// Round 7
// 332.147 us; speedup vs baseline: 1.3274x; 1.3274x over previous
//
#include <hip/hip_runtime.h>
#include <math.h>

#define Bn 32
#define Cn 256
#define Hn 64
#define Wn 64
#define MIP 8
#define OUP 256
#define BN_EPS 1e-5f

typedef float vfloat4 __attribute__((ext_vector_type(4)));  // native vec for NT ld/st

// ---------------------------------------------------------------------------
// R7 DIAGNOSTIC ROUND (stats x4; = the R5 probe that was lost to infra).
// R6 RESULT (apply x5 probe): apply + boundary = 43.1 us == its 268 MB
// stream floor (42.6 us @ 6.3 TB/s) -> apply is DONE, at roofline.
// This probe: dur_us delta vs 268.4 = 3 x (stats + boundary), splitting
// stats from {ymix + fixed harness cost}. Pre-registered: ~25 us => static
// model right, controllable slack exhausted (ROOFLINE next); ~55-75 us =>
// stats has 35-50 us of read-path slack, attack it next round.
// ---------------------------------------------------------------------------

// ---------------------------------------------------------------------------
// Kernel 1: per-(b,c) stats -> A[b][c][s], s in [0,128)
//   s<64:  a_h[h] = (rowsum[h] + softmax_h(rowmax)[h]) / 64
//   s>=64: a_w[w] = (colsum[w] + softmax_w(colmax)[w]) / 64
// (uses: mean_W(bias_h*bias_w) = bias_h/64 since softmax_w sums to 1)
// R2 LESSON: do NOT fuse stages via __threadfence()+atomic last-block pattern
// -- device-scope fences are chip-wide L2 writeback events on MI355X; 8192 of
// them serialized the machine (1161 us at 0.84% HBM).
// ---------------------------------------------------------------------------
__global__ __launch_bounds__(256) void stats_kernel(const float* __restrict__ x,
                                                    float* __restrict__ A) {
    const int bc = blockIdx.x;                       // b*Cn + c
    const float* xp = x + (size_t)bc * (Hn * Wn);
    __shared__ float tile[Hn * 65];                  // pitch 65: row & col conflict-free
    __shared__ float pmax[256], psum[256];
    const int t = threadIdx.x;

    // load 64x64 tile, float4-vectorized, coalesced (normal loads: WANT x in
    // L2/L3 for apply_kernel's re-read)
#pragma unroll
    for (int k = 0; k < 4; ++k) {
        int i4  = t + 256 * k;                       // float4 index 0..1023
        int idx = i4 * 4;
        int h = idx >> 6;
        int w = idx & 63;
        float4 v = ((const float4*)xp)[i4];
        float* dst = &tile[h * 65 + w];
        dst[0] = v.x; dst[1] = v.y; dst[2] = v.z; dst[3] = v.w;
    }
    __syncthreads();

    // half-range partial reductions (32 serial LDS reads each)
    {
        const int wv   = t >> 6;                     // wave id 0..3
        const int lane = t & 63;
        float m = -INFINITY, sm = 0.f;
        if ((wv & 1) == 0) {                         // waves 0,2: row lane, half (wv>>1)
            const int h = lane, w0 = (wv >> 1) * 32;
#pragma unroll 8
            for (int w = w0; w < w0 + 32; ++w) {
                float v = tile[h * 65 + w];
                m = fmaxf(m, v); sm += v;
            }
        } else {                                     // waves 1,3: col lane, half (wv>>1)
            const int w = lane, h0 = (wv >> 1) * 32;
#pragma unroll 8
            for (int h = h0; h < h0 + 32; ++h) {
                float v = tile[h * 65 + w];
                m = fmaxf(m, v); sm += v;
            }
        }
        pmax[t] = m; psum[t] = sm;
    }
    __syncthreads();

    if (t < 128) {
        float red_max = fmaxf(pmax[t], pmax[t + 128]);
        float red_sum = psum[t] + psum[t + 128];
        // softmax across the 64 lanes of this wave (wave0 = rows, wave1 = cols)
        float m = red_max;
#pragma unroll
        for (int off = 32; off > 0; off >>= 1) m = fmaxf(m, __shfl_xor(m, off));
        float e = __expf(red_max - m);
        float se = e;
#pragma unroll
        for (int off = 32; off > 0; off >>= 1) se += __shfl_xor(se, off);
        float a = (red_sum + e / se) * (1.0f / 64.0f);
        A[(size_t)bc * 128 + t] = a;
    }
}

// ---------------------------------------------------------------------------
// Kernel 2 (tiny): yact[b][m][s] = hswish(BN(sum_c w1[m][c] * A[b][c][s]))
//   1024 threads: s = t&127, K=256 split 8-way (32 c per thread), LDS combine.
// ---------------------------------------------------------------------------
__global__ __launch_bounds__(1024) void ymix_kernel(const float* __restrict__ A,
                                                    const float* __restrict__ w1,
                                                    const float* __restrict__ bn_gamma,
                                                    const float* __restrict__ bn_beta,
                                                    const float* __restrict__ bn_mean,
                                                    const float* __restrict__ bn_var,
                                                    float* __restrict__ yact) {
    const int b = blockIdx.x;
    const int t = threadIdx.x;
    const int s     = t & 127;
    const int chunk = t >> 7;                        // 0..7

    const float* Ab = A + (size_t)b * Cn * 128;

    float acc[MIP];
#pragma unroll
    for (int m = 0; m < MIP; ++m) acc[m] = 0.f;

    const int c0 = chunk * 32;
    for (int c = c0; c < c0 + 32; ++c) {
        float a = Ab[(size_t)c * 128 + s];           // coalesced over s
#pragma unroll
        for (int m = 0; m < MIP; ++m)
            acc[m] += w1[m * Cn + c] * a;            // wave-uniform scalar load
    }

    __shared__ float red[7][MIP][128];               // chunks 1..7
    if (chunk > 0) {
#pragma unroll
        for (int m = 0; m < MIP; ++m) red[chunk - 1][m][s] = acc[m];
    }
    __syncthreads();
    if (chunk == 0) {
#pragma unroll
        for (int m = 0; m < MIP; ++m) {
            float v = acc[m];
#pragma unroll
            for (int k = 0; k < 7; ++k) v += red[k][m][s];
            float sc = bn_gamma[m] * rsqrtf(bn_var[m] + BN_EPS);
            float sh = bn_beta[m] - bn_mean[m] * sc;
            v = v * sc + sh;
            v = v * fminf(fmaxf(v + 3.0f, 0.0f), 6.0f) * (1.0f / 6.0f); // hswish
            yact[(size_t)b * (MIP * 128) + m * 128 + s] = v;
        }
    }
}

// ---------------------------------------------------------------------------
// Kernel 3: per-(b,c) gate-compute + apply.
//   gs[s] = sigmoid(sum_m W2[c][m] * yact[b][m][s])  (W2 = wh for s<64, ww else)
//   out[b,c,h,w] = x[b,c,h,w] * gs[h] * gs[64+w]
//   NT loads for x (last use) + NT stores for out (never re-read).
// R6 MEASURED: 43.1 us incl. boundary = stream floor (268 MB @ 6.3 TB/s).
// ---------------------------------------------------------------------------
__global__ __launch_bounds__(256) void apply_kernel(const float* __restrict__ x,
                                                    const float* __restrict__ yact,
                                                    const float* __restrict__ wh,
                                                    const float* __restrict__ ww,
                                                    float* __restrict__ out) {
    const int bc = blockIdx.x;
    const int b  = bc >> 8;
    const int c  = bc & 255;
    const float* xp = x + (size_t)bc * (Hn * Wn);
    float* op = out + (size_t)bc * (Hn * Wn);

    __shared__ float gs[128];                        // [0,64): g_h, [64,128): g_w
    const int t = threadIdx.x;
    if (t < 128) {
        const float* w2row = (t < 64) ? (wh + c * MIP) : (ww + c * MIP); // wave-uniform
        const float* yb = yact + (size_t)b * (MIP * 128);
        float g = 0.f;
#pragma unroll
        for (int m = 0; m < MIP; ++m)
            g += w2row[m] * yb[m * 128 + t];         // coalesced over t
        gs[t] = 1.0f / (1.0f + __expf(-g));
    }
    __syncthreads();

#pragma unroll
    for (int k = 0; k < 4; ++k) {
        int i4  = t + 256 * k;
        int idx = i4 * 4;
        int h = idx >> 6;
        int w = idx & 63;                            // w % 4 == 0 -> aligned b128
        vfloat4 v = __builtin_nontemporal_load(&((const vfloat4*)xp)[i4]);
        float gh = gs[h];
        float4 gw = *(const float4*)&gs[64 + w];     // one ds_read_b128
        vfloat4 r;
        r.x = v.x * gh * gw.x;
        r.y = v.y * gh * gw.y;
        r.z = v.z * gh * gw.z;
        r.w = v.w * gh * gw.w;
        __builtin_nontemporal_store(r, &((vfloat4*)op)[i4]);
    }
}

extern "C" void kernel_launch(void* const* d_in, const int* in_sizes, int n_in,
                              void* d_out, int out_size, void* d_ws, size_t ws_size,
                              hipStream_t stream) {
    const float* x        = (const float*)d_in[0];
    const float* w1       = (const float*)d_in[1];
    const float* bn_gamma = (const float*)d_in[2];
    const float* bn_beta  = (const float*)d_in[3];
    const float* bn_mean  = (const float*)d_in[4];
    const float* bn_var   = (const float*)d_in[5];
    const float* wh       = (const float*)d_in[6];
    const float* ww       = (const float*)d_in[7];
    float* out = (float*)d_out;

    float* A    = (float*)d_ws;                            // Bn*Cn*128 floats = 4 MiB
    float* yact = A + (size_t)Bn * Cn * 128;               // Bn*MIP*128 floats = 128 KiB

    // stats x4: idempotent duplicates for the duration probe (see header note)
    stats_kernel<<<Bn * Cn, 256, 0, stream>>>(x, A);
    stats_kernel<<<Bn * Cn, 256, 0, stream>>>(x, A);
    stats_kernel<<<Bn * Cn, 256, 0, stream>>>(x, A);
    stats_kernel<<<Bn * Cn, 256, 0, stream>>>(x, A);
    ymix_kernel<<<Bn, 1024, 0, stream>>>(A, w1, bn_gamma, bn_beta, bn_mean,
                                         bn_var, yact);
    apply_kernel<<<Bn * Cn, 256, 0, stream>>>(x, yact, wh, ww, out);
}

// Round 10
// 270.094 us; speedup vs baseline: 1.6323x; 1.2297x over previous
//
#include <hip/hip_runtime.h>
#include <math.h>

#define Bn 32
#define Cn 256
#define Hn 64
#define Wn 64
#define MIP 8
#define OUP 256
#define BN_EPS 1e-5f

typedef float vfloat4 __attribute__((ext_vector_type(4)));  // native vec for NT ld/st

// ---------------------------------------------------------------------------
// R10 = R9 resubmitted verbatim (R9 hit a GPUAcquisitionTimeout; kernel never
// ran). Wide-ymix fix-as-probe. Ledger from duplication probes:
//   stats = 21.2 us == 134 MB HBM-read floor   (R7)
//   apply = 43.1 us == 268 MB stream floor     (R6)
//   ymix  = last unknown (32 blocks = 12.5% of CUs in the old shape).
// This round replaces ymix with a 128-block version (4x s-split, same
// reduction structure). Pre-registered: dur drops to ~205-235 => old ymix
// was the latency-bound slack, captured; dur ~268 +/- 5 => ymix was always
// launch-overhead-small => all kernels at floor, residual ~190 us is
// harness-fixed (two ~78 us in-window fills measured every iteration)
// => ROOFLINE declaration next round.
// R2 LESSON: no __threadfence()-based fusion (chip-wide L2 writeback; 8192
// fences serialized the machine at 0.84% HBM).
// ---------------------------------------------------------------------------

// ---------------------------------------------------------------------------
// Kernel 1: per-(b,c) stats -> A[b][c][s], s in [0,128)
//   s<64:  a_h[h] = (rowsum[h] + softmax_h(rowmax)[h]) / 64
//   s>=64: a_w[w] = (colsum[w] + softmax_w(colmax)[w]) / 64
// (uses: mean_W(bias_h*bias_w) = bias_h/64 since softmax_w sums to 1)
// R7 MEASURED: 21.2 us incl. boundary = HBM floor.
// ---------------------------------------------------------------------------
__global__ __launch_bounds__(256) void stats_kernel(const float* __restrict__ x,
                                                    float* __restrict__ A) {
    const int bc = blockIdx.x;                       // b*Cn + c
    const float* xp = x + (size_t)bc * (Hn * Wn);
    __shared__ float tile[Hn * 65];                  // pitch 65: row & col conflict-free
    __shared__ float pmax[256], psum[256];
    const int t = threadIdx.x;

    // load 64x64 tile, float4-vectorized, coalesced (normal loads: WANT x in
    // L2/L3 for apply_kernel's re-read)
#pragma unroll
    for (int k = 0; k < 4; ++k) {
        int i4  = t + 256 * k;                       // float4 index 0..1023
        int idx = i4 * 4;
        int h = idx >> 6;
        int w = idx & 63;
        float4 v = ((const float4*)xp)[i4];
        float* dst = &tile[h * 65 + w];
        dst[0] = v.x; dst[1] = v.y; dst[2] = v.z; dst[3] = v.w;
    }
    __syncthreads();

    // half-range partial reductions (32 serial LDS reads each)
    {
        const int wv   = t >> 6;                     // wave id 0..3
        const int lane = t & 63;
        float m = -INFINITY, sm = 0.f;
        if ((wv & 1) == 0) {                         // waves 0,2: row lane, half (wv>>1)
            const int h = lane, w0 = (wv >> 1) * 32;
#pragma unroll 8
            for (int w = w0; w < w0 + 32; ++w) {
                float v = tile[h * 65 + w];
                m = fmaxf(m, v); sm += v;
            }
        } else {                                     // waves 1,3: col lane, half (wv>>1)
            const int w = lane, h0 = (wv >> 1) * 32;
#pragma unroll 8
            for (int h = h0; h < h0 + 32; ++h) {
                float v = tile[h * 65 + w];
                m = fmaxf(m, v); sm += v;
            }
        }
        pmax[t] = m; psum[t] = sm;
    }
    __syncthreads();

    if (t < 128) {
        float red_max = fmaxf(pmax[t], pmax[t + 128]);
        float red_sum = psum[t] + psum[t + 128];
        // softmax across the 64 lanes of this wave (wave0 = rows, wave1 = cols)
        float m = red_max;
#pragma unroll
        for (int off = 32; off > 0; off >>= 1) m = fmaxf(m, __shfl_xor(m, off));
        float e = __expf(red_max - m);
        float se = e;
#pragma unroll
        for (int off = 32; off > 0; off >>= 1) se += __shfl_xor(se, off);
        float a = (red_sum + e / se) * (1.0f / 64.0f);
        A[(size_t)bc * 128 + t] = a;
    }
}

// ---------------------------------------------------------------------------
// Kernel 2: WIDE ymix. yact[b][m][s] = hswish(BN(sum_c w1[m][c]*A[b][c][s]))
// Grid Bn*4 = 128 blocks (b, s-quarter), 256 threads: sl = t&31 (local s),
// chunk = t>>5 (0..7, 32 c each). Same FP reduction order as the old ymix
// (c ascending within chunk; chunks combined k=0..6 after own acc) -> same
// bitwise result. 4x the blocks of the old shape, same per-thread chain.
// ---------------------------------------------------------------------------
__global__ __launch_bounds__(256) void ymix_kernel(const float* __restrict__ A,
                                                   const float* __restrict__ w1,
                                                   const float* __restrict__ bn_gamma,
                                                   const float* __restrict__ bn_beta,
                                                   const float* __restrict__ bn_mean,
                                                   const float* __restrict__ bn_var,
                                                   float* __restrict__ yact) {
    const int blk = blockIdx.x;
    const int b   = blk >> 2;
    const int sq  = blk & 3;                         // s-quarter
    const int t   = threadIdx.x;
    const int sl  = t & 31;                          // local s
    const int s   = sq * 32 + sl;
    const int chunk = t >> 5;                        // 0..7

    const float* Ab = A + (size_t)b * Cn * 128;

    float acc[MIP];
#pragma unroll
    for (int m = 0; m < MIP; ++m) acc[m] = 0.f;

    const int c0 = chunk * 32;
    for (int c = c0; c < c0 + 32; ++c) {
        float a = Ab[(size_t)c * 128 + s];           // 128B/half-wave, L2-resident
#pragma unroll
        for (int m = 0; m < MIP; ++m)
            acc[m] += w1[m * Cn + c] * a;            // wave-uniform scalar load
    }

    __shared__ float red[7][MIP][32];                // chunks 1..7 (7 KiB)
    if (chunk > 0) {
#pragma unroll
        for (int m = 0; m < MIP; ++m) red[chunk - 1][m][sl] = acc[m];
    }
    __syncthreads();
    if (chunk == 0) {
#pragma unroll
        for (int m = 0; m < MIP; ++m) {
            float v = acc[m];
#pragma unroll
            for (int k = 0; k < 7; ++k) v += red[k][m][sl];
            float sc = bn_gamma[m] * rsqrtf(bn_var[m] + BN_EPS);
            float sh = bn_beta[m] - bn_mean[m] * sc;
            v = v * sc + sh;
            v = v * fminf(fmaxf(v + 3.0f, 0.0f), 6.0f) * (1.0f / 6.0f); // hswish
            yact[(size_t)b * (MIP * 128) + m * 128 + s] = v;
        }
    }
}

// ---------------------------------------------------------------------------
// Kernel 3: per-(b,c) gate-compute + apply.
//   gs[s] = sigmoid(sum_m W2[c][m] * yact[b][m][s])  (W2 = wh for s<64, ww else)
//   out[b,c,h,w] = x[b,c,h,w] * gs[h] * gs[64+w]
//   NT loads for x (last use) + NT stores for out (never re-read).
// R6 MEASURED: 43.1 us incl. boundary = stream floor (268 MB @ 6.3 TB/s).
// ---------------------------------------------------------------------------
__global__ __launch_bounds__(256) void apply_kernel(const float* __restrict__ x,
                                                    const float* __restrict__ yact,
                                                    const float* __restrict__ wh,
                                                    const float* __restrict__ ww,
                                                    float* __restrict__ out) {
    const int bc = blockIdx.x;
    const int b  = bc >> 8;
    const int c  = bc & 255;
    const float* xp = x + (size_t)bc * (Hn * Wn);
    float* op = out + (size_t)bc * (Hn * Wn);

    __shared__ float gs[128];                        // [0,64): g_h, [64,128): g_w
    const int t = threadIdx.x;
    if (t < 128) {
        const float* w2row = (t < 64) ? (wh + c * MIP) : (ww + c * MIP); // wave-uniform
        const float* yb = yact + (size_t)b * (MIP * 128);
        float g = 0.f;
#pragma unroll
        for (int m = 0; m < MIP; ++m)
            g += w2row[m] * yb[m * 128 + t];         // coalesced over t
        gs[t] = 1.0f / (1.0f + __expf(-g));
    }
    __syncthreads();

#pragma unroll
    for (int k = 0; k < 4; ++k) {
        int i4  = t + 256 * k;
        int idx = i4 * 4;
        int h = idx >> 6;
        int w = idx & 63;                            // w % 4 == 0 -> aligned b128
        vfloat4 v = __builtin_nontemporal_load(&((const vfloat4*)xp)[i4]);
        float gh = gs[h];
        float4 gw = *(const float4*)&gs[64 + w];     // one ds_read_b128
        vfloat4 r;
        r.x = v.x * gh * gw.x;
        r.y = v.y * gh * gw.y;
        r.z = v.z * gh * gw.z;
        r.w = v.w * gh * gw.w;
        __builtin_nontemporal_store(r, &((vfloat4*)op)[i4]);
    }
}

extern "C" void kernel_launch(void* const* d_in, const int* in_sizes, int n_in,
                              void* d_out, int out_size, void* d_ws, size_t ws_size,
                              hipStream_t stream) {
    const float* x        = (const float*)d_in[0];
    const float* w1       = (const float*)d_in[1];
    const float* bn_gamma = (const float*)d_in[2];
    const float* bn_beta  = (const float*)d_in[3];
    const float* bn_mean  = (const float*)d_in[4];
    const float* bn_var   = (const float*)d_in[5];
    const float* wh       = (const float*)d_in[6];
    const float* ww       = (const float*)d_in[7];
    float* out = (float*)d_out;

    float* A    = (float*)d_ws;                            // Bn*Cn*128 floats = 4 MiB
    float* yact = A + (size_t)Bn * Cn * 128;               // Bn*MIP*128 floats = 128 KiB

    stats_kernel<<<Bn * Cn, 256, 0, stream>>>(x, A);
    ymix_kernel<<<Bn * 4, 256, 0, stream>>>(A, w1, bn_gamma, bn_beta, bn_mean,
                                            bn_var, yact);
    apply_kernel<<<Bn * Cn, 256, 0, stream>>>(x, yact, wh, ww, out);
}